// Round 3
// baseline (338.752 us; speedup 1.0000x reference)
//
#include <hip/hip_runtime.h>
#include <stdint.h>

// Problem constants (LieAction): B=16384, K=64, M=6, NUM_ACTIONS=16
#define BATCH 16384
#define KSUB 64
#define MDIM 6
#define MM 36            // floats per (b,k) block
#define NACT 16
#define F4PB 9           // float4 per block
#define WGT 128          // 2 waves per wg; thread pair (2k,2k+1) owns block k

typedef float f32x4 __attribute__((ext_vector_type(4)));
typedef float f32x2 __attribute__((ext_vector_type(2)));

// Kernel 1: R[a][k] = expm( act_params[a,k] * (L_k - L_k^T) ), fp32 Taylor n<=10.
// ||A||_inf <~ 0.05 -> truncation error ~1e-12. ~4 us, negligible.
__global__ void expm_table_kernel(const float* __restrict__ act_params, // [NACT,KSUB]
                                  const float* __restrict__ basis,      // [KSUB,36]
                                  float* __restrict__ Rtab)             // [NACT*KSUB,36]
{
    int gid = blockIdx.x * blockDim.x + threadIdx.x;
    if (gid >= NACT * KSUB) return;
    int a = gid / KSUB;
    int k = gid - a * KSUB;

    float L[MM];
#pragma unroll
    for (int i = 0; i < MM; ++i) L[i] = basis[k * MM + i];
    float p = act_params[a * KSUB + k];

    float A[MM];
#pragma unroll
    for (int i = 0; i < MDIM; ++i)
#pragma unroll
        for (int j = 0; j < MDIM; ++j)
            A[i * MDIM + j] = p * (L[i * MDIM + j] - L[j * MDIM + i]);

    float E[MM], T[MM];
#pragma unroll
    for (int i = 0; i < MM; ++i) { E[i] = 0.f; T[i] = 0.f; }
#pragma unroll
    for (int i = 0; i < MDIM; ++i) { E[i * MDIM + i] = 1.f; T[i * MDIM + i] = 1.f; }

    for (int n = 1; n <= 10; ++n) {
        float Tn[MM];
        float inv = 1.0f / (float)n;
#pragma unroll
        for (int i = 0; i < MDIM; ++i)
#pragma unroll
            for (int l = 0; l < MDIM; ++l) {
                float s = 0.f;
#pragma unroll
                for (int j = 0; j < MDIM; ++j)
                    s += A[i * MDIM + j] * T[j * MDIM + l];
                Tn[i * MDIM + l] = s * inv;
            }
#pragma unroll
        for (int i = 0; i < MM; ++i) { T[i] = Tn[i]; E[i] += Tn[i]; }
    }
#pragma unroll
    for (int i = 0; i < MM; ++i) Rtab[gid * MM + i] = E[i];
}

// Kernel 2: out[b,k] = R[act[b],k] @ G[b,k]  (6x6 @ 6x6, fp32)
// SPLIT-BLOCK, OCCUPANCY-FIRST structure:
//   wg = 128 threads (2 waves) per batch row b. Thread pair (2k, 2k+1)
//   owns block k: thread half h = tid&1 computes rows 3h..3h+2 of O.
//   Per-thread live state: R-half(18) + O-half(18) + streamed G(~8) + addr
//   ~= 50 VGPR -> fits the 64-VGPR bin -> 8 waves/SIMD = 32 waves/CU
//   (2x every previous version). LDS 9216 B x 16 wg/CU = 147 KB < 160 KB.
//
//   Staging: gf row -> LDS is a pure LINEAR copy (LDS pitch 36 = global
//   layout), register-staged with nontemporal loads (round 1/2 showed
//   global_load_lds DMA is ~10 us SLOWER here than reg staging: data is
//   read once, and nt loads skip cache pollution). b128 writes, 1 barrier.
//   G reads: pair-lanes read the same lds4[k*9+q] -> LDS same-address
//   broadcast (free); unique data 512 B/instr.
//   Output: written straight from registers, 9x nt f32x2 stores (72 B/lane,
//   wave covers contiguous 4.6 KB) -> no 2nd LDS round-trip, no 2nd barrier.
__global__ __launch_bounds__(WGT, 8) void apply_kernel(
    const f32x4* __restrict__ gf4,           // B*K*9 float4
    const int* __restrict__ act,             // [B] int32
    const float* __restrict__ Rtab,          // [NACT*KSUB*36] f32
    float* __restrict__ outf)                // B*K*36 f32
{
    __shared__ f32x4 lds4[KSUB * F4PB];      // 9216 B, linear (= global layout)
    const int tid = threadIdx.x;
    const int b = blockIdx.x;
    const int k = tid >> 1;                  // block 0..63
    const int h = tid & 1;                   // row-half 0/1
    const size_t base4 = (size_t)b * (KSUB * F4PB);

    // R-half loads first (L2-resident 147 KB table): 9x f32x2, 8B-aligned.
    // act[b] is wg-uniform -> scalar load.
    const int a = act[b];
    const f32x2* R2 = (const f32x2*)(Rtab + (size_t)((a << 6) + k) * MM + 18 * h);
    f32x2 r2[9];
#pragma unroll
    for (int m = 0; m < 9; ++m) r2[m] = R2[m];

    // stage gf row (576 float4) by 128 threads: 4 full rounds + half round
    f32x4 sv[4];
#pragma unroll
    for (int i = 0; i < 4; ++i)
        sv[i] = __builtin_nontemporal_load(&gf4[base4 + tid + (i << 7)]);
    f32x4 st;
    if (tid < 64) st = __builtin_nontemporal_load(&gf4[base4 + 512 + tid]);
#pragma unroll
    for (int i = 0; i < 4; ++i) lds4[tid + (i << 7)] = sv[i];
    if (tid < 64) lds4[512 + tid] = st;

    float R[18];
#pragma unroll
    for (int m = 0; m < 9; ++m) { R[2 * m] = r2[m].x; R[2 * m + 1] = r2[m].y; }

    __syncthreads();

    // O_half = R_half @ G, G streamed one float4 at a time from LDS.
    // G element idx=4q+e is G[j][l], j=idx/6, l=idx%6 (compile-time).
    const f32x4* grow = &lds4[k * F4PB];
    float O[18];
#pragma unroll
    for (int q = 0; q < F4PB; ++q) {
        f32x4 g = grow[q];
#pragma unroll
        for (int e = 0; e < 4; ++e) {
            const int idx = 4 * q + e;
            const int j = idx / MDIM;
            const int l = idx - j * MDIM;
            const float gv = g[e];
#pragma unroll
            for (int i = 0; i < 3; ++i) {
                if (idx < MDIM)              // j==0: first touch of O[:,l]
                    O[i * MDIM + l] = R[i * MDIM] * gv;
                else
                    O[i * MDIM + l] = fmaf(R[i * MDIM + j], gv, O[i * MDIM + l]);
            }
        }
    }

    // direct nt store of this thread's 18 floats (contiguous 72 B)
    f32x2* o2 = (f32x2*)(outf + (size_t)b * (KSUB * MM) + k * MM + 18 * h);
#pragma unroll
    for (int m = 0; m < 9; ++m) {
        f32x2 v; v.x = O[2 * m]; v.y = O[2 * m + 1];
        __builtin_nontemporal_store(v, &o2[m]);
    }
}

extern "C" void kernel_launch(void* const* d_in, const int* in_sizes, int n_in,
                              void* d_out, int out_size, void* d_ws, size_t ws_size,
                              hipStream_t stream) {
    const float* gf    = (const float*)d_in[0];  // group_feats f32 [B, K*36]
    const int*   act   = (const int*)d_in[1];    // [B] int32
    const float* ap    = (const float*)d_in[2];  // act_params f32 [16,64]
    const float* basis = (const float*)d_in[3];  // lie_alg_basis f32 [64,36]

    float* Rtab = (float*)d_ws;   // 16*64*36*4 = 147456 B of ws

    expm_table_kernel<<<16, 64, 0, stream>>>(ap, basis, Rtab);

    apply_kernel<<<BATCH, WGT, 0, stream>>>((const f32x4*)gf, act, Rtab,
                                            (float*)d_out);
}

// Round 6
// 299.681 us; speedup vs baseline: 1.1304x; 1.1304x over previous
//
#include <hip/hip_runtime.h>
#include <stdint.h>

// Problem constants (LieAction): B=16384, K=64, M=6, NUM_ACTIONS=16
#define BATCH 16384
#define KSUB 64
#define MDIM 6
#define MM 36            // floats per (b,k) block
#define NACT 16
#define F4PB 9           // float4 per block
#define WGT 128          // 2 waves per wg; thread pair (2k,2k+1) owns block k

typedef float f32x4 __attribute__((ext_vector_type(4)));
typedef float f32x2 __attribute__((ext_vector_type(2)));

// Kernel 1: R[a][k] = expm( act_params[a,k] * (L_k - L_k^T) ), fp32 Taylor n<=10.
// ||A||_inf <~ 0.05 -> truncation error ~1e-12. ~4 us, negligible.
__global__ void expm_table_kernel(const float* __restrict__ act_params, // [NACT,KSUB]
                                  const float* __restrict__ basis,      // [KSUB,36]
                                  float* __restrict__ Rtab)             // [NACT*KSUB,36]
{
    int gid = blockIdx.x * blockDim.x + threadIdx.x;
    if (gid >= NACT * KSUB) return;
    int a = gid / KSUB;
    int k = gid - a * KSUB;

    float L[MM];
#pragma unroll
    for (int i = 0; i < MM; ++i) L[i] = basis[k * MM + i];
    float p = act_params[a * KSUB + k];

    float A[MM];
#pragma unroll
    for (int i = 0; i < MDIM; ++i)
#pragma unroll
        for (int j = 0; j < MDIM; ++j)
            A[i * MDIM + j] = p * (L[i * MDIM + j] - L[j * MDIM + i]);

    float E[MM], T[MM];
#pragma unroll
    for (int i = 0; i < MM; ++i) { E[i] = 0.f; T[i] = 0.f; }
#pragma unroll
    for (int i = 0; i < MDIM; ++i) { E[i * MDIM + i] = 1.f; T[i * MDIM + i] = 1.f; }

    for (int n = 1; n <= 10; ++n) {
        float Tn[MM];
        float inv = 1.0f / (float)n;
#pragma unroll
        for (int i = 0; i < MDIM; ++i)
#pragma unroll
            for (int l = 0; l < MDIM; ++l) {
                float s = 0.f;
#pragma unroll
                for (int j = 0; j < MDIM; ++j)
                    s += A[i * MDIM + j] * T[j * MDIM + l];
                Tn[i * MDIM + l] = s * inv;
            }
#pragma unroll
        for (int i = 0; i < MM; ++i) { T[i] = Tn[i]; E[i] += Tn[i]; }
    }
#pragma unroll
    for (int i = 0; i < MM; ++i) Rtab[gid * MM + i] = E[i];
}

// Kernel 2: out[b,k] = R[act[b],k] @ G[b,k]  (6x6 @ 6x6, fp32)
//
// Counter-driven design (round-3 evidence):
//  * Stores: scattered stride-72 nt f32x2 stores caused 1.87x HBM write
//    amplification (WRITE_SIZE 282MB vs 151MB ideal) — nt bypasses the L2
//    partial-line merge. FIX: O-half -> LDS, barrier, then contiguous b128
//    nontemporal gather-stores (full 128B lines, the round-0-proven path).
//  * Loads: G straight to registers via 9x CACHED b128 loads at per-lane
//    stride 144. Each wave's 9 instrs fully cover its contiguous region, so
//    L2 merges the partial-line overlap (round-3 FETCH_SIZE confirmed no
//    read amplification). Removes the input LDS round-trip + one barrier.
//  * Pair-split compute: thread pair (2k,2k+1) owns block k, half h=tid&1
//    computes rows 3h..3h+2 of O. Round-3 counters: VGPR_Count=32 for this
//    structure — no pressure.
//  * LDS O writes: ds_write_b64 at byte 72*tid+8m -> dword bank (18t+2m)%32,
//    uniform 4/bank spread = data minimum, conflict-free.
__global__ __launch_bounds__(WGT, 6) void apply_kernel(
    const f32x4* __restrict__ gf4,           // B*K*9 float4
    const int* __restrict__ act,             // [B] int32
    const float* __restrict__ Rtab,          // [NACT*KSUB*36] f32
    f32x4* __restrict__ out4)                // B*K*9 float4
{
    __shared__ float lds[KSUB * MM];         // 9216 B = 576 float4
    const int tid = threadIdx.x;
    const int b = blockIdx.x;
    const int k = tid >> 1;                  // block 0..63
    const int h = tid & 1;                   // row-half 0/1
    const size_t base4 = (size_t)b * (KSUB * F4PB);

    // 1) G prefetch: 9x b128 cached loads, per-lane contiguous 144 B.
    const f32x4* g4 = &gf4[base4 + (size_t)k * F4PB];
    f32x4 g[F4PB];
#pragma unroll
    for (int q = 0; q < F4PB; ++q) g[q] = g4[q];

    // 2) R-half: 9x f32x2 from the L2-resident 147 KB table (act[b] is
    //    wg-uniform -> scalar load; half-row = 72 B contiguous, 8B-aligned).
    const int a = act[b];
    const f32x2* R2 = (const f32x2*)(Rtab + (size_t)((a << 6) + k) * MM + 18 * h);
    float R[18];
#pragma unroll
    for (int m = 0; m < 9; ++m) { f32x2 v = R2[m]; R[2 * m] = v.x; R[2 * m + 1] = v.y; }

    // 3) O_half = R_half @ G. G element idx=4q+e is G[j][l] (j=idx/6,
    //    l=idx%6, compile-time): O[i,l] += R[i,j]*g.
    float O[18];
#pragma unroll
    for (int q = 0; q < F4PB; ++q) {
#pragma unroll
        for (int e = 0; e < 4; ++e) {
            const int idx = 4 * q + e;
            const int j = idx / MDIM;
            const int l = idx - j * MDIM;
            const float gv = g[q][e];
#pragma unroll
            for (int i = 0; i < 3; ++i) {
                if (idx < MDIM)              // j==0: first touch of O[i,l]
                    O[i * MDIM + l] = R[i * MDIM] * gv;
                else
                    O[i * MDIM + l] = fmaf(R[i * MDIM + j], gv, O[i * MDIM + l]);
            }
        }
    }

    // 4) O-half -> LDS (9x ds_write_b64, uniform 4/bank spread)
    f32x2* o2 = (f32x2*)&lds[18 * tid];
#pragma unroll
    for (int m = 0; m < 9; ++m) {
        f32x2 v; v.x = O[2 * m]; v.y = O[2 * m + 1];
        o2[m] = v;
    }
    __syncthreads();

    // 5) contiguous full-line nt gather-stores: 576 float4 by 128 threads,
    //    4 full rounds + uniform-predicated half round.
    const f32x4* l4 = (const f32x4*)lds;
#pragma unroll
    for (int i = 0; i < 5; ++i) {
        int p4 = tid + (i << 7);
        if (p4 < KSUB * F4PB)
            __builtin_nontemporal_store(l4[p4], &out4[base4 + p4]);
    }
}

extern "C" void kernel_launch(void* const* d_in, const int* in_sizes, int n_in,
                              void* d_out, int out_size, void* d_ws, size_t ws_size,
                              hipStream_t stream) {
    const float* gf    = (const float*)d_in[0];  // group_feats f32 [B, K*36]
    const int*   act   = (const int*)d_in[1];    // [B] int32
    const float* ap    = (const float*)d_in[2];  // act_params f32 [16,64]
    const float* basis = (const float*)d_in[3];  // lie_alg_basis f32 [64,36]

    float* Rtab = (float*)d_ws;   // 16*64*36*4 = 147456 B of ws

    expm_table_kernel<<<16, 64, 0, stream>>>(ap, basis, Rtab);

    apply_kernel<<<BATCH, WGT, 0, stream>>>((const f32x4*)gf, act, Rtab,
                                            (f32x4*)d_out);
}

// Round 7
// 260.328 us; speedup vs baseline: 1.3013x; 1.1512x over previous
//
#include <hip/hip_runtime.h>
#include <stdint.h>

// Problem constants (LieAction): B=16384, K=64, M=6, NUM_ACTIONS=16
#define BATCH 16384
#define KSUB 64
#define MDIM 6
#define MM 36            // floats per (b,k) block
#define NACT 16
#define F4PB 9           // float4 per block
#define WGT 128          // 2 waves per wg; thread pair (2k,2k+1) owns block k

typedef float f32x4 __attribute__((ext_vector_type(4)));
typedef float f32x2 __attribute__((ext_vector_type(2)));

// Kernel 1: R[a][k] = expm( act_params[a,k] * (L_k - L_k^T) ), fp32 Taylor n<=10.
// ||A||_inf <~ 0.05 -> truncation error ~1e-12. ~4 us, negligible.
//
// OUTPUT LAYOUT (transposed for apply-side coalescing): Rtab is [a][m][lane]
// in float2 units: float2 index = a*1152 + m*128 + (2k+h), holding elements
// (E[18h+2m], E[18h+2m+1]) of block k. Apply's lane tid=2k+h reads chunk m at
// a contiguous-512B-per-instruction address a*1152 + m*128 + tid.
__global__ void expm_table_kernel(const float* __restrict__ act_params, // [NACT,KSUB]
                                  const float* __restrict__ basis,      // [KSUB,36]
                                  float* __restrict__ Rtab)             // [NACT*1152] f32x2
{
    int gid = blockIdx.x * blockDim.x + threadIdx.x;
    if (gid >= NACT * KSUB) return;
    int a = gid / KSUB;
    int k = gid - a * KSUB;

    float L[MM];
#pragma unroll
    for (int i = 0; i < MM; ++i) L[i] = basis[k * MM + i];
    float p = act_params[a * KSUB + k];

    float A[MM];
#pragma unroll
    for (int i = 0; i < MDIM; ++i)
#pragma unroll
        for (int j = 0; j < MDIM; ++j)
            A[i * MDIM + j] = p * (L[i * MDIM + j] - L[j * MDIM + i]);

    float E[MM], T[MM];
#pragma unroll
    for (int i = 0; i < MM; ++i) { E[i] = 0.f; T[i] = 0.f; }
#pragma unroll
    for (int i = 0; i < MDIM; ++i) { E[i * MDIM + i] = 1.f; T[i * MDIM + i] = 1.f; }

    for (int n = 1; n <= 10; ++n) {
        float Tn[MM];
        float inv = 1.0f / (float)n;
#pragma unroll
        for (int i = 0; i < MDIM; ++i)
#pragma unroll
            for (int l = 0; l < MDIM; ++l) {
                float s = 0.f;
#pragma unroll
                for (int j = 0; j < MDIM; ++j)
                    s += A[i * MDIM + j] * T[j * MDIM + l];
                Tn[i * MDIM + l] = s * inv;
            }
#pragma unroll
        for (int i = 0; i < MM; ++i) { T[i] = Tn[i]; E[i] += Tn[i]; }
    }

    // transposed store: [a][m][2k+h]
#pragma unroll
    for (int h = 0; h < 2; ++h)
#pragma unroll
        for (int m = 0; m < 9; ++m) {
            int idx = a * 1152 + m * 128 + 2 * k + h;   // float2 index
            Rtab[2 * idx]     = E[18 * h + 2 * m];
            Rtab[2 * idx + 1] = E[18 * h + 2 * m + 1];
        }
}

// Kernel 2: out[b,k] = R[act[b],k] @ G[b,k]  (6x6 @ 6x6, fp32)
//
// Round-6 post-mortem: apply was VMEM-front-end bound, not BW bound
// (2.05 TB/s at 79% occupancy, VALU 4%, WRITE exactly 151 MB). Per-lane
// stride-144 b128 G loads touch 72 cache lines PER INSTRUCTION (vs 8 for
// coalesced); stride-72 R loads touch 36. Fix: every global access is now
// full-line coalesced.
//  * Input: coalesced nt loads -> linear LDS (round-0/3-proven), barrier,
//    G read as 9x ds_read_b128 from own block row (pair-lanes broadcast;
//    dword banks 4(k+q) mod 32 -> uniform 4/bank = data minimum).
//  * R: transposed [a][m][lane] table layout (see expm kernel) -> each of
//    the 9 f32x2 loads is 512 B contiguous per instruction.
//  * Stores: O-half -> LDS, barrier, contiguous full-line nt b128 (round-6
//    proven: WRITE_SIZE exactly 147456 KB, no amplification).
//  * Correctness of in-place O-over-G in LDS without a 3rd barrier: thread
//    tid's O region (floats 18tid..18tid+17) lies INSIDE its own G region
//    (36k..36k+35, k=tid>>1), so per-thread aliasing forces read-before-
//    write order; cross-lane overlap is within the same wave (wave 0 owns
//    floats 0..1151, wave 1 owns 1152..2303) and DS ops from one wave
//    execute in issue order -> no race.
//  * 2 waves/wg, 9216 B LDS -> 16 wg/CU = 32 waves/CU; VGPR ~40 (round 6
//    measured 32 for the same compute structure) -> fits the 64-reg bin.
__global__ __launch_bounds__(WGT, 8) void apply_kernel(
    const f32x4* __restrict__ gf4,           // B*K*9 float4
    const int* __restrict__ act,             // [B] int32
    const float* __restrict__ Rtab,          // [NACT*1152] f32x2, [a][m][lane]
    f32x4* __restrict__ out4)                // B*K*9 float4
{
    __shared__ float lds[KSUB * MM];         // 9216 B = 576 float4
    f32x4* lds4 = (f32x4*)lds;
    const int tid = threadIdx.x;
    const int b = blockIdx.x;
    const int k = tid >> 1;                  // block 0..63
    const size_t base4 = (size_t)b * (KSUB * F4PB);

    const int a = act[b];                    // wg-uniform -> s_load, issue early

    // 1) coalesced nt staging loads (4 full rounds + half round)
    f32x4 sv[4];
#pragma unroll
    for (int i = 0; i < 4; ++i)
        sv[i] = __builtin_nontemporal_load(&gf4[base4 + tid + (i << 7)]);
    f32x4 st;
    if (tid < 64) st = __builtin_nontemporal_load(&gf4[base4 + 512 + tid]);

    // 2) R-half: 9x f32x2, coalesced via transposed table (512 B/instr).
    //    147 KB table is L1/L2-resident after first touch.
    const f32x2* Rt = (const f32x2*)Rtab + (size_t)a * 1152 + tid;
    float R[18];
#pragma unroll
    for (int m = 0; m < 9; ++m) {
        f32x2 v = Rt[m * 128];
        R[2 * m] = v.x; R[2 * m + 1] = v.y;
    }

    // 3) stage to LDS (contiguous b128, 8 dwords/bank = data minimum)
#pragma unroll
    for (int i = 0; i < 4; ++i) lds4[tid + (i << 7)] = sv[i];
    if (tid < 64) lds4[512 + tid] = st;
    __syncthreads();

    // 4) O_half = R_half @ G, G streamed one float4 at a time from own block
    //    row in LDS (pair-lanes same address -> broadcast). G element
    //    idx=4q+e is G[j][l] (j=idx/6, l=idx%6, compile-time).
    const f32x4* grow = &lds4[k * F4PB];
    float O[18];
#pragma unroll
    for (int q = 0; q < F4PB; ++q) {
        f32x4 g = grow[q];
#pragma unroll
        for (int e = 0; e < 4; ++e) {
            const int idx = 4 * q + e;
            const int j = idx / MDIM;
            const int l = idx - j * MDIM;
            const float gv = g[e];
#pragma unroll
            for (int i = 0; i < 3; ++i) {
                if (idx < MDIM)              // j==0: first touch of O[i,l]
                    O[i * MDIM + l] = R[i * MDIM] * gv;
                else
                    O[i * MDIM + l] = fmaf(R[i * MDIM + j], gv, O[i * MDIM + l]);
            }
        }
    }

    // 5) O-half -> LDS in place (per-thread aliasing orders this after the
    //    G reads; see header comment). 9x ds_write_b64.
    f32x2* o2 = (f32x2*)&lds[18 * tid];
#pragma unroll
    for (int m = 0; m < 9; ++m) {
        f32x2 v; v.x = O[2 * m]; v.y = O[2 * m + 1];
        o2[m] = v;
    }
    __syncthreads();

    // 6) contiguous full-line nt gather-stores (576 float4 by 128 threads)
#pragma unroll
    for (int i = 0; i < 4; ++i) {
        int p4 = tid + (i << 7);
        __builtin_nontemporal_store(lds4[p4], &out4[base4 + p4]);
    }
    if (tid < 64) {
        int p4 = 512 + tid;
        __builtin_nontemporal_store(lds4[p4], &out4[base4 + p4]);
    }
}

extern "C" void kernel_launch(void* const* d_in, const int* in_sizes, int n_in,
                              void* d_out, int out_size, void* d_ws, size_t ws_size,
                              hipStream_t stream) {
    const float* gf    = (const float*)d_in[0];  // group_feats f32 [B, K*36]
    const int*   act   = (const int*)d_in[1];    // [B] int32
    const float* ap    = (const float*)d_in[2];  // act_params f32 [16,64]
    const float* basis = (const float*)d_in[3];  // lie_alg_basis f32 [64,36]

    float* Rtab = (float*)d_ws;   // 16*1152*8 = 147456 B of ws

    expm_table_kernel<<<16, 64, 0, stream>>>(ap, basis, Rtab);

    apply_kernel<<<BATCH, WGT, 0, stream>>>((const f32x4*)gf, act, Rtab,
                                            (f32x4*)d_out);
}